// Round 9
// baseline (426.042 us; speedup 1.0000x reference)
//
#include <hip/hip_runtime.h>
#include <math.h>

#define B_SZ 512
#define S_SZ 512
#define E_NUM 8
#define F_DIM 20
#define BM 16          // pairs per RNN block (full MFMA N-tile)
#define MAXBLK 71      // max sum_e ceil(cnt_e/16) = 71

typedef __attribute__((ext_vector_type(8))) _Float16 f16x8;
typedef __attribute__((ext_vector_type(4))) float f32x4;
#define MFMAH(a, b, c) __builtin_amdgcn_mfma_f32_16x16x32_f16(a, b, c, 0, 0, 0)

// pack two f32 -> f16 pair (RNE) in one dword
__device__ __forceinline__ unsigned pk16(float a, float b) {
  _Float16 ha = (_Float16)a, hb = (_Float16)b;
  unsigned short ua = __builtin_bit_cast(unsigned short, ha);
  unsigned short ub = __builtin_bit_cast(unsigned short, hb);
  return (unsigned)ua | ((unsigned)ub << 16);
}
__device__ __forceinline__ float ftanh(float x) {
  float e = __expf(x + x);  // +inf -> rcp(inf)=0 -> 1; -inf -> e=0 -> -1
  float r;
  asm("v_rcp_f32 %0, %1" : "=v"(r) : "v"(e + 1.0f));
  return fmaf(-2.0f, r, 1.0f);
}

// raw barrier: waits LDS ops only; global loads stay in flight
#define BAR() do {                                        \
  asm volatile("s_waitcnt lgkmcnt(0)" ::: "memory");      \
  __builtin_amdgcn_s_barrier();                           \
  asm volatile("" ::: "memory");                          \
} while (0)

// ------ Kernel 0: one-time W_ih f16 2-split (lo pre-scaled x1024) ------
__global__ __launch_bounds__(256) void k_wsplit16(
    const float* __restrict__ W, _Float16* __restrict__ Wh,
    _Float16* __restrict__ Wl) {
  int idx = (blockIdx.x * 256 + threadIdx.x) * 8;  // 64 blocks cover 131072
  float4 a = *(const float4*)(W + idx);
  float4 b = *(const float4*)(W + idx + 4);
  float v[8] = {a.x, a.y, a.z, a.w, b.x, b.y, b.z, b.w};
  f16x8 h, l;
#pragma unroll
  for (int j = 0; j < 8; j++) {
    _Float16 hh = (_Float16)v[j];
    h[j] = hh;
    l[j] = (_Float16)((v[j] - (float)hh) * 1024.0f);
  }
  *(f16x8*)(Wh + idx) = h;
  *(f16x8*)(Wl + idx) = l;
}

// ---------------- Kernel 1: x_mean + logits ----------------
__global__ __launch_bounds__(512) void k_mean_logits(
    const float* __restrict__ x, const float* __restrict__ w_gate,
    float* __restrict__ logits) {
  __shared__ float sm[512];
  __shared__ float xm[128];
  int b = blockIdx.x;
  int t = threadIdx.x;
  int i = t & 127, s0 = t >> 7;
  const float* xb = x + (size_t)b * (S_SZ * 128);
  float acc = 0.f;
  for (int s = s0; s < S_SZ; s += 4) acc += xb[s * 128 + i];
  sm[t] = acc;
  __syncthreads();
  if (t < 128)
    xm[t] = (sm[t] + sm[t + 128] + sm[t + 256] + sm[t + 384]) * (1.0f / 512.0f);
  __syncthreads();
  if (t < E_NUM) {
    float acc2 = 0.f;
    for (int ii = 0; ii < 128; ii++) acc2 += xm[ii] * w_gate[ii * E_NUM + t];
    logits[b * E_NUM + t] = acc2;
  }
}

// ------- Kernel 2: top-2 gates + CV^2 loss + expert compaction -------
__global__ __launch_bounds__(512) void k_gate(
    const float* __restrict__ logits, float* __restrict__ sel_g,
    int* __restrict__ pair_b, int* __restrict__ pair_of,
    int* __restrict__ blk_e, int* __restrict__ blk_p0,
    int* __restrict__ blk_nr, int* __restrict__ nblk,
    float* __restrict__ loss_out) {
  __shared__ float gmat[512][8];
  __shared__ int cnt[8], base[8], pos[8];
  __shared__ float imps[8];
  int t = threadIdx.x;
  if (t < 8) { cnt[t] = 0; pos[t] = 0; }
  float lv[8];
#pragma unroll
  for (int e = 0; e < 8; e++) {
    lv[e] = logits[t * 8 + e];
    gmat[t][e] = 0.f;
  }
  __syncthreads();
  float v0 = -INFINITY, v1 = -INFINITY;
  int i0 = 0, i1 = 0;
#pragma unroll
  for (int e = 0; e < 8; e++) {
    float v = lv[e];
    if (v > v0) { v1 = v0; i1 = i0; v0 = v; i0 = e; }
    else if (v > v1) { v1 = v; i1 = e; }
  }
  float ex = expf(v1 - v0);
  float inv = 1.0f / (1.0f + ex);
  float g0 = inv, g1 = ex * inv;
  gmat[t][i0] = g0;
  gmat[t][i1] = g1;
  atomicAdd(&cnt[i0], 1);
  atomicAdd(&cnt[i1], 1);
  sel_g[t * 2] = g0;
  sel_g[t * 2 + 1] = g1;
  __syncthreads();
  if (t == 0) {
    int o = 0;
    for (int e = 0; e < 8; e++) { base[e] = o; o += cnt[e]; }
    int nb = 0;
    for (int e = 0; e < 8; e++)
      for (int off = 0; off < cnt[e]; off += BM) {
        blk_e[nb] = e;
        blk_p0[nb] = base[e] + off;
        blk_nr[nb] = min(BM, cnt[e] - off);
        nb++;
      }
    *nblk = nb;
  }
  if (t < 8) {
    float s = 0.f;
    for (int bb = 0; bb < 512; bb++) s += gmat[bb][t];
    imps[t] = s;
  }
  __syncthreads();
  {
    int r = atomicAdd(&pos[i0], 1);
    int p = base[i0] + r;
    pair_b[p] = t;
    pair_of[t * 2] = p;
  }
  {
    int r = atomicAdd(&pos[i1], 1);
    int p = base[i1] + r;
    pair_b[p] = t;
    pair_of[t * 2 + 1] = p;
  }
  if (t == 0) {
    float mi = 0.f, ml = 0.f;
#pragma unroll
    for (int e = 0; e < 8; e++) { mi += imps[e]; ml += (float)cnt[e]; }
    mi *= 0.125f; ml *= 0.125f;
    float vi = 0.f, vl = 0.f;
#pragma unroll
    for (int e = 0; e < 8; e++) {
      float di = imps[e] - mi; vi += di * di;
      float dl = (float)cnt[e] - ml; vl += dl * dl;
    }
    vi *= (1.0f / 7.0f);
    vl *= (1.0f / 7.0f);
    loss_out[0] = 0.01f * (vi / (mi * mi + 1e-10f) + vl / (ml * ml + 1e-10f));
  }
}

// ---- Kernel 3: fused producer/consumer MoE-RNN (deep rings + setprio) ----
// waves 0-3: producers — X ring 4-slot, P ring 4-slot, run 2 steps ahead.
// waves 4-7: consumers — P preloaded to registers (off critical path),
//   depth-2 MFMA chains, setprio(1) around MFMA cluster, H f16 ping-pong.
__global__ __launch_bounds__(512, 2) void k_moe(
    const float* __restrict__ x, const _Float16* __restrict__ Wih_h,
    const _Float16* __restrict__ Wih_l, const float* __restrict__ W_hh,
    const float* __restrict__ b_ih, const float* __restrict__ b_hh,
    const float* __restrict__ fc1_w, const float* __restrict__ fc1_b,
    const float* __restrict__ fc2_w, const float* __restrict__ fc2_b,
    const int* __restrict__ pair_b, const int* __restrict__ blk_e,
    const int* __restrict__ blk_p0, const int* __restrict__ blk_nr,
    const int* __restrict__ nblk, float* __restrict__ outp) {
  __shared__ unsigned short sX[4][2048];  // f16 X ring, 4 x 4KB
  __shared__ float sP[4][2048];           // f32 P ring, 4 x 8KB
  __shared__ unsigned short sH[2][2048];  // f16 H ping-pong, 2 x 4KB
  __shared__ float sZ[BM * F_DIM];

  int blk = blockIdx.x;
  if (blk >= *nblk) return;
  int e = blk_e[blk], p0 = blk_p0[blk], nr = blk_nr[blk];
  int tid = threadIdx.x;
  int lane = tid & 63, g = lane >> 4, ln = lane & 15;
  int wv = tid >> 6;

  char* sxb = (char*)&sX[0][0];
  char* spb = (char*)&sP[0][0];
  char* shb = (char*)&sH[0][0];

  // zero H slot 0 (4KB)
  ((unsigned int*)shb)[tid] = 0;
  ((unsigned int*)shb)[tid + 512] = 0;

  // fragment-read offsets (16 rows x 128 f16, XOR swizzle)
  int swz = (ln & 7) << 4;
  int rdoff[4];
#pragma unroll
  for (int ks = 0; ks < 4; ks++) rdoff[ks] = (ln * 256 + ks * 64 + g * 16) ^ swz;

  const f32x4 Z4 = {0.f, 0.f, 0.f, 0.f};

  if (wv < 4) {
    // ================== PRODUCER (M-tiles 2wv, 2wv+1) ==================
    int w = wv;
    f16x8 wih_h[2][4], wih_l[2][4];
#pragma unroll
    for (int m = 0; m < 2; m++) {
      int row = (2 * w + m) * 16 + ln;
      const _Float16* bh = Wih_h + (size_t)e * 16384 + row * 128 + g * 8;
      const _Float16* bl = Wih_l + (size_t)e * 16384 + row * 128 + g * 8;
#pragma unroll
      for (int ks = 0; ks < 4; ks++) {
        wih_h[m][ks] = *(const f16x8*)(bh + ks * 32);
        wih_l[m][ks] = *(const f16x8*)(bl + ks * 32);
      }
    }
    f32x4 biasv[2];
#pragma unroll
    for (int m = 0; m < 2; m++)
#pragma unroll
      for (int r = 0; r < 4; r++) {
        int h = (2 * w + m) * 16 + g * 4 + r;
        biasv[m][r] = b_ih[e * 128 + h] + b_hh[e * 128 + h];
      }
    int pwoff[2];
#pragma unroll
    for (int m = 0; m < 2; m++)
      pwoff[m] = (2 * w + m) * 1024 + g * 256 + ln * 16;

    // staging: lane handles row 4w+(lane>>4), elems k0..k0+7
    int srow = 4 * w + (lane >> 4);
    int k0 = (lane & 15) * 8;
    int sb = pair_b[p0 + (srow < nr ? srow : 0)];
    const char* xsrc = (const char*)x + (size_t)sb * (S_SZ * 512) + k0 * 4;
    int stoff = (srow * 256 + k0 * 2) ^ ((srow & 7) << 4);

    float4 xa0, xa1, xb0, xb1;

#define LDX(B0, B1, STEP)                                                    \
  do {                                                                       \
    B0 = *(const float4*)(xsrc + (size_t)(STEP) * 512);                      \
    B1 = *(const float4*)(xsrc + (size_t)(STEP) * 512 + 16);                 \
  } while (0)

#define STG(WS, B0, B1)                                                      \
  do {                                                                       \
    float v[8] = {B0.x, B0.y, B0.z, B0.w, B1.x, B1.y, B1.z, B1.w};           \
    f16x8 hx;                                                                \
    _Pragma("unroll") for (int j = 0; j < 8; j++) hx[j] = (_Float16)v[j];    \
    *(f16x8*)(sxb + ((WS) << 12) + stoff) = hx;                              \
  } while (0)

#define PRD(S)                                                               \
  do {                                                                       \
    f16x8 Xf0 = *(const f16x8*)(sxb + ((S) << 12) + rdoff[0]);               \
    f16x8 Xf1 = *(const f16x8*)(sxb + ((S) << 12) + rdoff[1]);               \
    f16x8 Xf2 = *(const f16x8*)(sxb + ((S) << 12) + rdoff[2]);               \
    f16x8 Xf3 = *(const f16x8*)(sxb + ((S) << 12) + rdoff[3]);               \
    _Pragma("unroll") for (int m = 0; m < 2; m++) {                          \
      f32x4 pA = biasv[m];                                                   \
      pA = MFMAH(wih_h[m][0], Xf0, pA);                                      \
      pA = MFMAH(wih_h[m][1], Xf1, pA);                                      \
      pA = MFMAH(wih_h[m][2], Xf2, pA);                                      \
      pA = MFMAH(wih_h[m][3], Xf3, pA);                                      \
      f32x4 pB = Z4;                                                         \
      pB = MFMAH(wih_l[m][0], Xf0, pB);                                      \
      pB = MFMAH(wih_l[m][1], Xf1, pB);                                      \
      pB = MFMAH(wih_l[m][2], Xf2, pB);                                      \
      pB = MFMAH(wih_l[m][3], Xf3, pB);                                      \
      _Pragma("unroll") for (int r = 0; r < 4; r++)                          \
          pA[r] = fmaf(pB[r], 0.0009765625f, pA[r]);                         \
      *(f32x4*)(spb + ((S) << 13) + pwoff[m]) = pA;                          \
    }                                                                        \
  } while (0)

    // prologue: stage X slots 0..2, preload step 3 regs
    LDX(xa0, xa1, 0);
    LDX(xb0, xb1, 1);
    STG(0, xa0, xa1);
    STG(1, xb0, xb1);
    LDX(xa0, xa1, 2);
    STG(2, xa0, xa1);
    LDX(xb0, xb1, 3);
    BAR();  // A: X0..2 + H0 visible
    PRD(0);
    PRD(1);
    BAR();  // B: P0,P1 visible

    // interval r: PRD(slot (r+2)&3); STG(slot (r+3)&3, step r+3);
    //             LDX(step r+4); BAR.
#pragma unroll 1
    for (int r4 = 0; r4 < 504; r4 += 4) {
      PRD(2); STG(3, xb0, xb1); LDX(xa0, xa1, r4 + 4); BAR();
      PRD(3); STG(0, xa0, xa1); LDX(xb0, xb1, r4 + 5); BAR();
      PRD(0); STG(1, xb0, xb1); LDX(xa0, xa1, r4 + 6); BAR();
      PRD(1); STG(2, xa0, xa1); LDX(xb0, xb1, r4 + 7); BAR();
    }
    // tail r = 504..511
    PRD(2); STG(3, xb0, xb1); LDX(xa0, xa1, 508); BAR();  // 504
    PRD(3); STG(0, xa0, xa1); LDX(xb0, xb1, 509); BAR();  // 505
    PRD(0); STG(1, xb0, xb1); LDX(xa0, xa1, 510); BAR();  // 506
    PRD(1); STG(2, xa0, xa1); LDX(xb0, xb1, 511); BAR();  // 507
    PRD(2); STG(3, xb0, xb1); BAR();                      // 508
    PRD(3); BAR();                                        // 509 -> P[511]
    BAR();                                                // 510
    BAR();                                                // 511
#undef PRD
#undef STG
#undef LDX
  } else {
    // ================== CONSUMER (M-tiles 2w2, 2w2+1) ==================
    int w2 = wv - 4;
    f16x8 wh[2][4], wl[2][4];
#pragma unroll
    for (int m = 0; m < 2; m++) {
      int row = (2 * w2 + m) * 16 + ln;
      const float* bh = W_hh + (size_t)e * 16384 + row * 128 + g * 8;
#pragma unroll
      for (int ks = 0; ks < 4; ks++) {
        float4 a = *(const float4*)(bh + ks * 32);
        float4 b = *(const float4*)(bh + ks * 32 + 4);
        float v[8] = {a.x, a.y, a.z, a.w, b.x, b.y, b.z, b.w};
        f16x8 h, l;
#pragma unroll
        for (int j = 0; j < 8; j++) {
          _Float16 hh = (_Float16)v[j];
          h[j] = hh;
          l[j] = (_Float16)((v[j] - (float)hh) * 1024.0f);
        }
        wh[m][ks] = h;
        wl[m][ks] = l;
      }
    }
    int proff[2], wroff[2];
#pragma unroll
    for (int m = 0; m < 2; m++) {
      proff[m] = (2 * w2 + m) * 1024 + g * 256 + ln * 16;
      wroff[m] = (ln * 256 + (2 * w2 + m) * 32 + g * 8) ^ swz;
    }

// step r: use PU (P[r], in regs), prefetch PN <- P slot PSN=(r+1)&3,
// H read slot RS=r&1, H write slot RS^1, setprio(1) on MFMA cluster.
#define CRD(RS, PSN, PU0, PU1, PN0, PN1)                                     \
  do {                                                                       \
    f16x8 Hf0 = *(const f16x8*)(shb + (RS)*4096 + rdoff[0]);                 \
    f16x8 Hf1 = *(const f16x8*)(shb + (RS)*4096 + rdoff[1]);                 \
    f16x8 Hf2 = *(const f16x8*)(shb + (RS)*4096 + rdoff[2]);                 \
    f16x8 Hf3 = *(const f16x8*)(shb + (RS)*4096 + rdoff[3]);                 \
    PN0 = *(const f32x4*)(spb + ((PSN) << 13) + proff[0]);                   \
    PN1 = *(const f32x4*)(spb + ((PSN) << 13) + proff[1]);                   \
    __builtin_amdgcn_s_setprio(1);                                           \
    f32x4 a0 = MFMAH(wh[0][0], Hf0, PU0); a0 = MFMAH(wh[0][1], Hf1, a0);     \
    f32x4 b0 = MFMAH(wh[0][2], Hf2, Z4);  b0 = MFMAH(wh[0][3], Hf3, b0);     \
    f32x4 c0 = MFMAH(wl[0][0], Hf0, Z4);  c0 = MFMAH(wl[0][1], Hf1, c0);     \
    f32x4 d0 = MFMAH(wl[0][2], Hf2, Z4);  d0 = MFMAH(wl[0][3], Hf3, d0);     \
    f32x4 a1 = MFMAH(wh[1][0], Hf0, PU1); a1 = MFMAH(wh[1][1], Hf1, a1);     \
    f32x4 b1 = MFMAH(wh[1][2], Hf2, Z4);  b1 = MFMAH(wh[1][3], Hf3, b1);     \
    f32x4 c1 = MFMAH(wl[1][0], Hf0, Z4);  c1 = MFMAH(wl[1][1], Hf1, c1);     \
    f32x4 d1 = MFMAH(wl[1][2], Hf2, Z4);  d1 = MFMAH(wl[1][3], Hf3, d1);     \
    __builtin_amdgcn_s_setprio(0);                                           \
    f32x4 pre0, pre1;                                                        \
    _Pragma("unroll") for (int r = 0; r < 4; r++) {                          \
      pre0[r] = (a0[r] + b0[r]) + (c0[r] + d0[r]) * 0.0009765625f;           \
      pre1[r] = (a1[r] + b1[r]) + (c1[r] + d1[r]) * 0.0009765625f;           \
    }                                                                        \
    {                                                                        \
      float t0 = ftanh(pre0[0]), t1 = ftanh(pre0[1]);                        \
      float t2 = ftanh(pre0[2]), t3 = ftanh(pre0[3]);                        \
      uint2 hv = {pk16(t0, t1), pk16(t2, t3)};                               \
      *(uint2*)(shb + ((RS) ^ 1) * 4096 + wroff[0]) = hv;                    \
    }                                                                        \
    {                                                                        \
      float t0 = ftanh(pre1[0]), t1 = ftanh(pre1[1]);                        \
      float t2 = ftanh(pre1[2]), t3 = ftanh(pre1[3]);                        \
      uint2 hv = {pk16(t0, t1), pk16(t2, t3)};                               \
      *(uint2*)(shb + ((RS) ^ 1) * 4096 + wroff[1]) = hv;                    \
    }                                                                        \
    BAR();                                                                   \
  } while (0)

    f32x4 prA0, prA1, prB0, prB1;
    BAR();  // A
    BAR();  // B: P0,P1 visible
    prA0 = *(const f32x4*)(spb + proff[0]);  // P[0] -> regs
    prA1 = *(const f32x4*)(spb + proff[1]);
#pragma unroll 1
    for (int it = 0; it < 128; it++) {
      CRD(0, 1, prA0, prA1, prB0, prB1);
      CRD(1, 2, prB0, prB1, prA0, prA1);
      CRD(0, 3, prA0, prA1, prB0, prB1);
      CRD(1, 0, prB0, prB1, prA0, prA1);
    }
#undef CRD
  }

  // ---- MLP head: h_512 (f16) in sH slot 0 ----
  {
    int p = tid >> 5, q = tid & 31;
    if (q < F_DIM) {
      float acc = fc1_b[e * F_DIM + q];
      const float* w1 = fc1_w + (size_t)e * (F_DIM * 128) + q * 128;
      for (int k = 0; k < 128; k++) {
        int off = (p * 256 + k * 2) ^ ((p & 7) << 4);
        float h = (float)(*(const _Float16*)(shb + off));
        acc = fmaf(h, w1[k], acc);
      }
      sZ[p * F_DIM + q] = ftanh(acc);
    }
  }
  __syncthreads();
  if (tid < BM) {
    float acc = fc2_b[e];
#pragma unroll
    for (int f = 0; f < F_DIM; f++)
      acc += sZ[tid * F_DIM + f] * fc2_w[e * F_DIM + f];
    if (tid < nr) outp[p0 + tid] = acc;
  }
}

// ---------------- Kernel 4: weighted combine ----------------
__global__ void k_combine(const float* __restrict__ sel_g,
                          const int* __restrict__ pair_of,
                          const float* __restrict__ outp,
                          float* __restrict__ y) {
  int b = blockIdx.x * blockDim.x + threadIdx.x;
  if (b < B_SZ)
    y[b] = sel_g[2 * b] * outp[pair_of[2 * b]] +
           sel_g[2 * b + 1] * outp[pair_of[2 * b + 1]];
}

extern "C" void kernel_launch(void* const* d_in, const int* in_sizes, int n_in,
                              void* d_out, int out_size, void* d_ws,
                              size_t ws_size, hipStream_t stream) {
  (void)in_sizes; (void)n_in; (void)out_size; (void)ws_size;
  const float* x      = (const float*)d_in[0];
  const float* w_gate = (const float*)d_in[1];
  const float* W_ih   = (const float*)d_in[2];
  const float* W_hh   = (const float*)d_in[3];
  const float* b_ih   = (const float*)d_in[4];
  const float* b_hh   = (const float*)d_in[5];
  const float* fc1_w  = (const float*)d_in[6];
  const float* fc1_b  = (const float*)d_in[7];
  const float* fc2_w  = (const float*)d_in[8];
  const float* fc2_b  = (const float*)d_in[9];
  float* out = (float*)d_out;  // [0..511] = y, [512] = loss

  float* logits = (float*)d_ws;            // 4096 f32
  float* sel_g  = logits + 4096;           // 1024 f32
  int*   pair_b = (int*)(sel_g + 1024);    // 1024 i32
  int*   pair_of= pair_b + 1024;           // 1024 i32
  int*   blk_e  = pair_of + 1024;          // 128 i32
  int*   blk_p0 = blk_e + 128;             // 128 i32
  int*   blk_nr = blk_p0 + 128;            // 128 i32
  int*   nblk   = blk_nr + 128;            // 8 i32
  float* outp   = (float*)(nblk + 8);      // 1024 f32
  _Float16* Wih_h = (_Float16*)((char*)d_ws + 65536);  // 256 KB
  _Float16* Wih_l = Wih_h + 131072;                    // 256 KB

  k_wsplit16<<<64, 256, 0, stream>>>(W_ih, Wih_h, Wih_l);
  k_mean_logits<<<B_SZ, 512, 0, stream>>>(x, w_gate, logits);
  k_gate<<<1, 512, 0, stream>>>(logits, sel_g, pair_b, pair_of, blk_e, blk_p0,
                                blk_nr, nblk, out + 512);
  k_moe<<<MAXBLK, 512, 0, stream>>>(x, Wih_h, Wih_l, W_hh, b_ih, b_hh, fc1_w,
                                    fc1_b, fc2_w, fc2_b, pair_b, blk_e,
                                    blk_p0, blk_nr, nblk, outp);
  k_combine<<<2, 256, 0, stream>>>(sel_g, pair_of, outp, out);
}

// Round 10
// 425.843 us; speedup vs baseline: 1.0005x; 1.0005x over previous
//
#include <hip/hip_runtime.h>
#include <math.h>

#define B_SZ 512
#define S_SZ 512
#define E_NUM 8
#define F_DIM 20
#define BM 16          // pairs per RNN block (full MFMA N-tile)
#define MAXBLK 71      // max sum_e ceil(cnt_e/16) = 71

typedef __attribute__((ext_vector_type(8))) _Float16 f16x8;
typedef __attribute__((ext_vector_type(4))) float f32x4;
#define MFMAH(a, b, c) __builtin_amdgcn_mfma_f32_16x16x32_f16(a, b, c, 0, 0, 0)

// pack two f32 -> f16 pair (RNE) in one dword
__device__ __forceinline__ unsigned pk16(float a, float b) {
  _Float16 ha = (_Float16)a, hb = (_Float16)b;
  unsigned short ua = __builtin_bit_cast(unsigned short, ha);
  unsigned short ub = __builtin_bit_cast(unsigned short, hb);
  return (unsigned)ua | ((unsigned)ub << 16);
}
__device__ __forceinline__ float ftanh(float x) {
  float e = __expf(x + x);  // +inf -> rcp(inf)=0 -> 1; -inf -> e=0 -> -1
  float r;
  asm("v_rcp_f32 %0, %1" : "=v"(r) : "v"(e + 1.0f));
  return fmaf(-2.0f, r, 1.0f);
}

// raw barrier: waits LDS ops only; global loads stay in flight
#define BAR() do {                                        \
  asm volatile("s_waitcnt lgkmcnt(0)" ::: "memory");      \
  __builtin_amdgcn_s_barrier();                           \
  asm volatile("" ::: "memory");                          \
} while (0)

// ------ Kernel 0: one-time W_ih f16 2-split (lo pre-scaled x1024) ------
__global__ __launch_bounds__(256) void k_wsplit16(
    const float* __restrict__ W, _Float16* __restrict__ Wh,
    _Float16* __restrict__ Wl) {
  int idx = (blockIdx.x * 256 + threadIdx.x) * 8;  // 64 blocks cover 131072
  float4 a = *(const float4*)(W + idx);
  float4 b = *(const float4*)(W + idx + 4);
  float v[8] = {a.x, a.y, a.z, a.w, b.x, b.y, b.z, b.w};
  f16x8 h, l;
#pragma unroll
  for (int j = 0; j < 8; j++) {
    _Float16 hh = (_Float16)v[j];
    h[j] = hh;
    l[j] = (_Float16)((v[j] - (float)hh) * 1024.0f);
  }
  *(f16x8*)(Wh + idx) = h;
  *(f16x8*)(Wl + idx) = l;
}

// ---------------- Kernel 1: x_mean + logits ----------------
__global__ __launch_bounds__(512) void k_mean_logits(
    const float* __restrict__ x, const float* __restrict__ w_gate,
    float* __restrict__ logits) {
  __shared__ float sm[512];
  __shared__ float xm[128];
  int b = blockIdx.x;
  int t = threadIdx.x;
  int i = t & 127, s0 = t >> 7;
  const float* xb = x + (size_t)b * (S_SZ * 128);
  float acc = 0.f;
  for (int s = s0; s < S_SZ; s += 4) acc += xb[s * 128 + i];
  sm[t] = acc;
  __syncthreads();
  if (t < 128)
    xm[t] = (sm[t] + sm[t + 128] + sm[t + 256] + sm[t + 384]) * (1.0f / 512.0f);
  __syncthreads();
  if (t < E_NUM) {
    float acc2 = 0.f;
    for (int ii = 0; ii < 128; ii++) acc2 += xm[ii] * w_gate[ii * E_NUM + t];
    logits[b * E_NUM + t] = acc2;
  }
}

// ------- Kernel 2: top-2 gates + CV^2 loss + expert compaction -------
__global__ __launch_bounds__(512) void k_gate(
    const float* __restrict__ logits, float* __restrict__ sel_g,
    int* __restrict__ pair_b, int* __restrict__ pair_of,
    int* __restrict__ blk_e, int* __restrict__ blk_p0,
    int* __restrict__ blk_nr, int* __restrict__ nblk,
    float* __restrict__ loss_out) {
  __shared__ float gmat[512][8];
  __shared__ int cnt[8], base[8], pos[8];
  __shared__ float imps[8];
  int t = threadIdx.x;
  if (t < 8) { cnt[t] = 0; pos[t] = 0; }
  float lv[8];
#pragma unroll
  for (int e = 0; e < 8; e++) {
    lv[e] = logits[t * 8 + e];
    gmat[t][e] = 0.f;
  }
  __syncthreads();
  float v0 = -INFINITY, v1 = -INFINITY;
  int i0 = 0, i1 = 0;
#pragma unroll
  for (int e = 0; e < 8; e++) {
    float v = lv[e];
    if (v > v0) { v1 = v0; i1 = i0; v0 = v; i0 = e; }
    else if (v > v1) { v1 = v; i1 = e; }
  }
  float ex = expf(v1 - v0);
  float inv = 1.0f / (1.0f + ex);
  float g0 = inv, g1 = ex * inv;
  gmat[t][i0] = g0;
  gmat[t][i1] = g1;
  atomicAdd(&cnt[i0], 1);
  atomicAdd(&cnt[i1], 1);
  sel_g[t * 2] = g0;
  sel_g[t * 2 + 1] = g1;
  __syncthreads();
  if (t == 0) {
    int o = 0;
    for (int e = 0; e < 8; e++) { base[e] = o; o += cnt[e]; }
    int nb = 0;
    for (int e = 0; e < 8; e++)
      for (int off = 0; off < cnt[e]; off += BM) {
        blk_e[nb] = e;
        blk_p0[nb] = base[e] + off;
        blk_nr[nb] = min(BM, cnt[e] - off);
        nb++;
      }
    *nblk = nb;
  }
  if (t < 8) {
    float s = 0.f;
    for (int bb = 0; bb < 512; bb++) s += gmat[bb][t];
    imps[t] = s;
  }
  __syncthreads();
  {
    int r = atomicAdd(&pos[i0], 1);
    int p = base[i0] + r;
    pair_b[p] = t;
    pair_of[t * 2] = p;
  }
  {
    int r = atomicAdd(&pos[i1], 1);
    int p = base[i1] + r;
    pair_b[p] = t;
    pair_of[t * 2 + 1] = p;
  }
  if (t == 0) {
    float mi = 0.f, ml = 0.f;
#pragma unroll
    for (int e = 0; e < 8; e++) { mi += imps[e]; ml += (float)cnt[e]; }
    mi *= 0.125f; ml *= 0.125f;
    float vi = 0.f, vl = 0.f;
#pragma unroll
    for (int e = 0; e < 8; e++) {
      float di = imps[e] - mi; vi += di * di;
      float dl = (float)cnt[e] - ml; vl += dl * dl;
    }
    vi *= (1.0f / 7.0f);
    vl *= (1.0f / 7.0f);
    loss_out[0] = 0.01f * (vi / (mi * mi + 1e-10f) + vl / (ml * ml + 1e-10f));
  }
}

// ---- Kernel 3: fused producer/consumer MoE-RNN (deep rings + setprio) ----
// waves 0-3: producers — X ring 4-slot, P ring 4-slot, run 2 steps ahead.
// waves 4-7: consumers — P preloaded to registers (off critical path),
//   depth-2 MFMA chains, setprio(1) around MFMA cluster, H f16 ping-pong.
__global__ __launch_bounds__(512, 2) void k_moe(
    const float* __restrict__ x, const _Float16* __restrict__ Wih_h,
    const _Float16* __restrict__ Wih_l, const float* __restrict__ W_hh,
    const float* __restrict__ b_ih, const float* __restrict__ b_hh,
    const float* __restrict__ fc1_w, const float* __restrict__ fc1_b,
    const float* __restrict__ fc2_w, const float* __restrict__ fc2_b,
    const int* __restrict__ pair_b, const int* __restrict__ blk_e,
    const int* __restrict__ blk_p0, const int* __restrict__ blk_nr,
    const int* __restrict__ nblk, float* __restrict__ outp) {
  __shared__ unsigned short sX[4][2048];  // f16 X ring, 4 x 4KB
  __shared__ float sP[4][2048];           // f32 P ring, 4 x 8KB
  __shared__ unsigned short sH[2][2048];  // f16 H ping-pong, 2 x 4KB
  __shared__ float sZ[BM * F_DIM];

  int blk = blockIdx.x;
  if (blk >= *nblk) return;
  int e = blk_e[blk], p0 = blk_p0[blk], nr = blk_nr[blk];
  int tid = threadIdx.x;
  int lane = tid & 63, g = lane >> 4, ln = lane & 15;
  int wv = tid >> 6;

  char* sxb = (char*)&sX[0][0];
  char* spb = (char*)&sP[0][0];
  char* shb = (char*)&sH[0][0];

  // zero H slot 0 (4KB)
  ((unsigned int*)shb)[tid] = 0;
  ((unsigned int*)shb)[tid + 512] = 0;

  // fragment-read offsets (16 rows x 128 f16, XOR swizzle)
  int swz = (ln & 7) << 4;
  int rdoff[4];
#pragma unroll
  for (int ks = 0; ks < 4; ks++) rdoff[ks] = (ln * 256 + ks * 64 + g * 16) ^ swz;

  const f32x4 Z4 = {0.f, 0.f, 0.f, 0.f};

  if (wv < 4) {
    // ================== PRODUCER (M-tiles 2wv, 2wv+1) ==================
    int w = wv;
    f16x8 wih_h[2][4], wih_l[2][4];
#pragma unroll
    for (int m = 0; m < 2; m++) {
      int row = (2 * w + m) * 16 + ln;
      const _Float16* bh = Wih_h + (size_t)e * 16384 + row * 128 + g * 8;
      const _Float16* bl = Wih_l + (size_t)e * 16384 + row * 128 + g * 8;
#pragma unroll
      for (int ks = 0; ks < 4; ks++) {
        wih_h[m][ks] = *(const f16x8*)(bh + ks * 32);
        wih_l[m][ks] = *(const f16x8*)(bl + ks * 32);
      }
    }
    f32x4 biasv[2];
#pragma unroll
    for (int m = 0; m < 2; m++)
#pragma unroll
      for (int r = 0; r < 4; r++) {
        int h = (2 * w + m) * 16 + g * 4 + r;
        biasv[m][r] = b_ih[e * 128 + h] + b_hh[e * 128 + h];
      }
    int pwoff[2];
#pragma unroll
    for (int m = 0; m < 2; m++)
      pwoff[m] = (2 * w + m) * 1024 + g * 256 + ln * 16;

    // staging: lane handles row 4w+(lane>>4), elems k0..k0+7
    int srow = 4 * w + (lane >> 4);
    int k0 = (lane & 15) * 8;
    int sb = pair_b[p0 + (srow < nr ? srow : 0)];
    const char* xsrc = (const char*)x + (size_t)sb * (S_SZ * 512) + k0 * 4;
    int stoff = (srow * 256 + k0 * 2) ^ ((srow & 7) << 4);

    float4 xa0, xa1, xb0, xb1;

#define LDX(B0, B1, STEP)                                                    \
  do {                                                                       \
    B0 = *(const float4*)(xsrc + (size_t)(STEP) * 512);                      \
    B1 = *(const float4*)(xsrc + (size_t)(STEP) * 512 + 16);                 \
  } while (0)

#define STG(WS, B0, B1)                                                      \
  do {                                                                       \
    float v[8] = {B0.x, B0.y, B0.z, B0.w, B1.x, B1.y, B1.z, B1.w};           \
    f16x8 hx;                                                                \
    _Pragma("unroll") for (int j = 0; j < 8; j++) hx[j] = (_Float16)v[j];    \
    *(f16x8*)(sxb + ((WS) << 12) + stoff) = hx;                              \
  } while (0)

#define PRD(S)                                                               \
  do {                                                                       \
    f16x8 Xf0 = *(const f16x8*)(sxb + ((S) << 12) + rdoff[0]);               \
    f16x8 Xf1 = *(const f16x8*)(sxb + ((S) << 12) + rdoff[1]);               \
    f16x8 Xf2 = *(const f16x8*)(sxb + ((S) << 12) + rdoff[2]);               \
    f16x8 Xf3 = *(const f16x8*)(sxb + ((S) << 12) + rdoff[3]);               \
    _Pragma("unroll") for (int m = 0; m < 2; m++) {                          \
      f32x4 pA = biasv[m];                                                   \
      pA = MFMAH(wih_h[m][0], Xf0, pA);                                      \
      pA = MFMAH(wih_h[m][1], Xf1, pA);                                      \
      pA = MFMAH(wih_h[m][2], Xf2, pA);                                      \
      pA = MFMAH(wih_h[m][3], Xf3, pA);                                      \
      f32x4 pB = Z4;                                                         \
      pB = MFMAH(wih_l[m][0], Xf0, pB);                                      \
      pB = MFMAH(wih_l[m][1], Xf1, pB);                                      \
      pB = MFMAH(wih_l[m][2], Xf2, pB);                                      \
      pB = MFMAH(wih_l[m][3], Xf3, pB);                                      \
      _Pragma("unroll") for (int r = 0; r < 4; r++)                          \
          pA[r] = fmaf(pB[r], 0.0009765625f, pA[r]);                         \
      *(f32x4*)(spb + ((S) << 13) + pwoff[m]) = pA;                          \
    }                                                                        \
  } while (0)

    // prologue: stage X slots 0..2, preload step 3 regs
    LDX(xa0, xa1, 0);
    LDX(xb0, xb1, 1);
    STG(0, xa0, xa1);
    STG(1, xb0, xb1);
    LDX(xa0, xa1, 2);
    STG(2, xa0, xa1);
    LDX(xb0, xb1, 3);
    BAR();  // A: X0..2 + H0 visible
    PRD(0);
    PRD(1);
    BAR();  // B: P0,P1 visible

    // interval r: PRD(slot (r+2)&3); STG(slot (r+3)&3, step r+3);
    //             LDX(step r+4); BAR.
#pragma unroll 1
    for (int r4 = 0; r4 < 504; r4 += 4) {
      PRD(2); STG(3, xb0, xb1); LDX(xa0, xa1, r4 + 4); BAR();
      PRD(3); STG(0, xa0, xa1); LDX(xb0, xb1, r4 + 5); BAR();
      PRD(0); STG(1, xb0, xb1); LDX(xa0, xa1, r4 + 6); BAR();
      PRD(1); STG(2, xa0, xa1); LDX(xb0, xb1, r4 + 7); BAR();
    }
    // tail r = 504..511
    PRD(2); STG(3, xb0, xb1); LDX(xa0, xa1, 508); BAR();  // 504
    PRD(3); STG(0, xa0, xa1); LDX(xb0, xb1, 509); BAR();  // 505
    PRD(0); STG(1, xb0, xb1); LDX(xa0, xa1, 510); BAR();  // 506
    PRD(1); STG(2, xa0, xa1); LDX(xb0, xb1, 511); BAR();  // 507
    PRD(2); STG(3, xb0, xb1); BAR();                      // 508
    PRD(3); BAR();                                        // 509 -> P[511]
    BAR();                                                // 510
    BAR();                                                // 511
#undef PRD
#undef STG
#undef LDX
  } else {
    // ================== CONSUMER (M-tiles 2w2, 2w2+1) ==================
    int w2 = wv - 4;
    f16x8 wh[2][4], wl[2][4];
#pragma unroll
    for (int m = 0; m < 2; m++) {
      int row = (2 * w2 + m) * 16 + ln;
      const float* bh = W_hh + (size_t)e * 16384 + row * 128 + g * 8;
#pragma unroll
      for (int ks = 0; ks < 4; ks++) {
        float4 a = *(const float4*)(bh + ks * 32);
        float4 b = *(const float4*)(bh + ks * 32 + 4);
        float v[8] = {a.x, a.y, a.z, a.w, b.x, b.y, b.z, b.w};
        f16x8 h, l;
#pragma unroll
        for (int j = 0; j < 8; j++) {
          _Float16 hh = (_Float16)v[j];
          h[j] = hh;
          l[j] = (_Float16)((v[j] - (float)hh) * 1024.0f);
        }
        wh[m][ks] = h;
        wl[m][ks] = l;
      }
    }
    int proff[2], wroff[2];
#pragma unroll
    for (int m = 0; m < 2; m++) {
      proff[m] = (2 * w2 + m) * 1024 + g * 256 + ln * 16;
      wroff[m] = (ln * 256 + (2 * w2 + m) * 32 + g * 8) ^ swz;
    }

// step r: use PU (P[r], in regs), prefetch PN <- P slot PSN=(r+1)&3,
// H read slot RS=r&1, H write slot RS^1, setprio(1) on MFMA cluster.
#define CRD(RS, PSN, PU0, PU1, PN0, PN1)                                     \
  do {                                                                       \
    f16x8 Hf0 = *(const f16x8*)(shb + (RS)*4096 + rdoff[0]);                 \
    f16x8 Hf1 = *(const f16x8*)(shb + (RS)*4096 + rdoff[1]);                 \
    f16x8 Hf2 = *(const f16x8*)(shb + (RS)*4096 + rdoff[2]);                 \
    f16x8 Hf3 = *(const f16x8*)(shb + (RS)*4096 + rdoff[3]);                 \
    PN0 = *(const f32x4*)(spb + ((PSN) << 13) + proff[0]);                   \
    PN1 = *(const f32x4*)(spb + ((PSN) << 13) + proff[1]);                   \
    __builtin_amdgcn_s_setprio(1);                                           \
    f32x4 a0 = MFMAH(wh[0][0], Hf0, PU0); a0 = MFMAH(wh[0][1], Hf1, a0);     \
    f32x4 b0 = MFMAH(wh[0][2], Hf2, Z4);  b0 = MFMAH(wh[0][3], Hf3, b0);     \
    f32x4 c0 = MFMAH(wl[0][0], Hf0, Z4);  c0 = MFMAH(wl[0][1], Hf1, c0);     \
    f32x4 d0 = MFMAH(wl[0][2], Hf2, Z4);  d0 = MFMAH(wl[0][3], Hf3, d0);     \
    f32x4 a1 = MFMAH(wh[1][0], Hf0, PU1); a1 = MFMAH(wh[1][1], Hf1, a1);     \
    f32x4 b1 = MFMAH(wh[1][2], Hf2, Z4);  b1 = MFMAH(wh[1][3], Hf3, b1);     \
    f32x4 c1 = MFMAH(wl[1][0], Hf0, Z4);  c1 = MFMAH(wl[1][1], Hf1, c1);     \
    f32x4 d1 = MFMAH(wl[1][2], Hf2, Z4);  d1 = MFMAH(wl[1][3], Hf3, d1);     \
    __builtin_amdgcn_s_setprio(0);                                           \
    f32x4 pre0, pre1;                                                        \
    _Pragma("unroll") for (int r = 0; r < 4; r++) {                          \
      pre0[r] = (a0[r] + b0[r]) + (c0[r] + d0[r]) * 0.0009765625f;           \
      pre1[r] = (a1[r] + b1[r]) + (c1[r] + d1[r]) * 0.0009765625f;           \
    }                                                                        \
    {                                                                        \
      float t0 = ftanh(pre0[0]), t1 = ftanh(pre0[1]);                        \
      float t2 = ftanh(pre0[2]), t3 = ftanh(pre0[3]);                        \
      uint2 hv = {pk16(t0, t1), pk16(t2, t3)};                               \
      *(uint2*)(shb + ((RS) ^ 1) * 4096 + wroff[0]) = hv;                    \
    }                                                                        \
    {                                                                        \
      float t0 = ftanh(pre1[0]), t1 = ftanh(pre1[1]);                        \
      float t2 = ftanh(pre1[2]), t3 = ftanh(pre1[3]);                        \
      uint2 hv = {pk16(t0, t1), pk16(t2, t3)};                               \
      *(uint2*)(shb + ((RS) ^ 1) * 4096 + wroff[1]) = hv;                    \
    }                                                                        \
    BAR();                                                                   \
  } while (0)

    f32x4 prA0, prA1, prB0, prB1;
    BAR();  // A
    BAR();  // B: P0,P1 visible
    prA0 = *(const f32x4*)(spb + proff[0]);  // P[0] -> regs
    prA1 = *(const f32x4*)(spb + proff[1]);
#pragma unroll 1
    for (int it = 0; it < 128; it++) {
      CRD(0, 1, prA0, prA1, prB0, prB1);
      CRD(1, 2, prB0, prB1, prA0, prA1);
      CRD(0, 3, prA0, prA1, prB0, prB1);
      CRD(1, 0, prB0, prB1, prA0, prA1);
    }
#undef CRD
  }

  // ---- MLP head: h_512 (f16) in sH slot 0 ----
  {
    int p = tid >> 5, q = tid & 31;
    if (q < F_DIM) {
      float acc = fc1_b[e * F_DIM + q];
      const float* w1 = fc1_w + (size_t)e * (F_DIM * 128) + q * 128;
      for (int k = 0; k < 128; k++) {
        int off = (p * 256 + k * 2) ^ ((p & 7) << 4);
        float h = (float)(*(const _Float16*)(shb + off));
        acc = fmaf(h, w1[k], acc);
      }
      sZ[p * F_DIM + q] = ftanh(acc);
    }
  }
  __syncthreads();
  if (tid < BM) {
    float acc = fc2_b[e];
#pragma unroll
    for (int f = 0; f < F_DIM; f++)
      acc += sZ[tid * F_DIM + f] * fc2_w[e * F_DIM + f];
    if (tid < nr) outp[p0 + tid] = acc;
  }
}

// ---------------- Kernel 4: weighted combine ----------------
__global__ void k_combine(const float* __restrict__ sel_g,
                          const int* __restrict__ pair_of,
                          const float* __restrict__ outp,
                          float* __restrict__ y) {
  int b = blockIdx.x * blockDim.x + threadIdx.x;
  if (b < B_SZ)
    y[b] = sel_g[2 * b] * outp[pair_of[2 * b]] +
           sel_g[2 * b + 1] * outp[pair_of[2 * b + 1]];
}

extern "C" void kernel_launch(void* const* d_in, const int* in_sizes, int n_in,
                              void* d_out, int out_size, void* d_ws,
                              size_t ws_size, hipStream_t stream) {
  (void)in_sizes; (void)n_in; (void)out_size; (void)ws_size;
  const float* x      = (const float*)d_in[0];
  const float* w_gate = (const float*)d_in[1];
  const float* W_ih   = (const float*)d_in[2];
  const float* W_hh   = (const float*)d_in[3];
  const float* b_ih   = (const float*)d_in[4];
  const float* b_hh   = (const float*)d_in[5];
  const float* fc1_w  = (const float*)d_in[6];
  const float* fc1_b  = (const float*)d_in[7];
  const float* fc2_w  = (const float*)d_in[8];
  const float* fc2_b  = (const float*)d_in[9];
  float* out = (float*)d_out;  // [0..511] = y, [512] = loss

  float* logits = (float*)d_ws;            // 4096 f32
  float* sel_g  = logits + 4096;           // 1024 f32
  int*   pair_b = (int*)(sel_g + 1024);    // 1024 i32
  int*   pair_of= pair_b + 1024;           // 1024 i32
  int*   blk_e  = pair_of + 1024;          // 128 i32
  int*   blk_p0 = blk_e + 128;             // 128 i32
  int*   blk_nr = blk_p0 + 128;            // 128 i32
  int*   nblk   = blk_nr + 128;            // 8 i32
  float* outp   = (float*)(nblk + 8);      // 1024 f32
  _Float16* Wih_h = (_Float16*)((char*)d_ws + 65536);  // 256 KB
  _Float16* Wih_l = Wih_h + 131072;                    // 256 KB

  k_wsplit16<<<64, 256, 0, stream>>>(W_ih, Wih_h, Wih_l);
  k_mean_logits<<<B_SZ, 512, 0, stream>>>(x, w_gate, logits);
  k_gate<<<1, 512, 0, stream>>>(logits, sel_g, pair_b, pair_of, blk_e, blk_p0,
                                blk_nr, nblk, out + 512);
  k_moe<<<MAXBLK, 512, 0, stream>>>(x, Wih_h, Wih_l, W_hh, b_ih, b_hh, fc1_w,
                                    fc1_b, fc2_w, fc2_b, pair_b, blk_e,
                                    blk_p0, blk_nr, nblk, outp);
  k_combine<<<2, 256, 0, stream>>>(sel_g, pair_of, outp, out);
}